// Round 1
// baseline (1098.670 us; speedup 1.0000x reference)
//
#include <hip/hip_runtime.h>
#include <hip/hip_bf16.h>
#include <stdint.h>

#define BB  1024
#define SS  20
#define DD  128
#define G3  384      // 3*D
#define NII 100000
#define KXX 136      // D + R

typedef float  f32x4  __attribute__((ext_vector_type(4)));
typedef __bf16 bf16x8 __attribute__((ext_vector_type(8)));

__device__ __forceinline__ unsigned short f2bf(float x) {
  uint32_t u = __float_as_uint(x);
  uint32_t r = (u + 0x7fffu + ((u >> 16) & 1u)) >> 16;   // RNE
  return (unsigned short)r;
}

__device__ __forceinline__ float sigf(float x) { return 1.f / (1.f + expf(-x)); }

// ---------------- K1: zero sums/counts for touched items ----------------
__global__ __launch_bounds__(256) void k_zero_seg(const int* __restrict__ items,
                                                  float* __restrict__ sums,
                                                  float* __restrict__ counts) {
  int tid = blockIdx.x * 256 + threadIdx.x;
  int p = tid >> 5, c = tid & 31;
  if (p >= BB * SS) return;
  int it = items[p];
  f32x4 z = {0.f, 0.f, 0.f, 0.f};
  *(f32x4*)(sums + (size_t)it * DD + c * 4) = z;
  if (c == 0) counts[it] = 0.f;
}

// ---------------- K2: WhT4[k4][g][4] = Wh[g][4k4..4k4+3] ----------------
__global__ __launch_bounds__(256) void k_whT4(const float* __restrict__ Wh,
                                              float* __restrict__ WhT4) {
  int id = blockIdx.x * 256 + threadIdx.x;   // 384*32 total
  if (id >= G3 * 32) return;
  int g = id >> 5, k4 = id & 31;
  f32x4 v = *(const f32x4*)(Wh + g * DD + k4 * 4);
  *(f32x4*)(WhT4 + ((size_t)k4 * G3 + g) * 4) = v;
}

// ---------------- K3: M = W_u @ W_i^T  (128x128) ----------------
__global__ __launch_bounds__(256) void k_M(const float* __restrict__ Wu,
                                           const float* __restrict__ Wi,
                                           float* __restrict__ M) {
  int idx = blockIdx.x * 256 + threadIdx.x;  // 16384 total
  int k1 = idx >> 7, k2 = idx & 127;
  float acc = 0.f;
  for (int e = 0; e < DD; ++e)
    acc = fmaf(Wu[k1 * DD + e], Wi[k2 * DD + e], acc);
  M[idx] = acc;
}

// ---------------- K4: gx[p][g] = x[p] . Wx[g] + bx[g] ----------------
// p = b*S + s; x[p] = [table[item], rew*1_8]; reward folded via wxr[g].
__global__ __launch_bounds__(256) void k_gx(const int* __restrict__ items,
                                            const float* __restrict__ rew,
                                            const float* __restrict__ table,
                                            const float* __restrict__ Wx,
                                            const float* __restrict__ bx,
                                            float* __restrict__ gx) {
  __shared__ float Wl[96][140];
  __shared__ float Al[16][128];
  __shared__ float rl[16];
  int gt = blockIdx.x & 3, pt = blockIdx.x >> 2;
  int g0 = gt * 96, p0 = pt * 16;
  int t = threadIdx.x;
  for (int i = t; i < 96 * 34; i += 256) {           // 136 cols = 34 float4
    int r = i / 34, c = i % 34;
    f32x4 v = *(const f32x4*)(Wx + (size_t)(g0 + r) * KXX + c * 4);
    *(f32x4*)&Wl[r][c * 4] = v;
  }
  for (int i = t; i < 16 * 32; i += 256) {
    int r = i >> 5, c = i & 31;
    int it = items[p0 + r];
    *(f32x4*)&Al[r][c * 4] = *(const f32x4*)(table + (size_t)it * DD + c * 4);
  }
  if (t < 16) rl[t] = rew[p0 + t];
  __syncthreads();

  int tg = t & 31, pq = (t >> 5) & 7;
  float acc[2][3] = {};
  for (int k4 = 0; k4 < 32; ++k4) {
    f32x4 a0 = *(f32x4*)&Al[pq][k4 * 4];
    f32x4 a1 = *(f32x4*)&Al[pq + 8][k4 * 4];
#pragma unroll
    for (int u = 0; u < 3; ++u) {
      f32x4 w = *(f32x4*)&Wl[tg + 32 * u][k4 * 4];
      acc[0][u] += a0.x * w.x + a0.y * w.y + a0.z * w.z + a0.w * w.w;
      acc[1][u] += a1.x * w.x + a1.y * w.y + a1.z * w.z + a1.w * w.w;
    }
  }
#pragma unroll
  for (int u = 0; u < 3; ++u) {
    int gl = tg + 32 * u, g = g0 + gl;
    float wxr = 0.f;
#pragma unroll
    for (int q = 0; q < 8; ++q) wxr += Wl[gl][128 + q];
    float bxv = bx[g];
#pragma unroll
    for (int i2 = 0; i2 < 2; ++i2) {
      int p = p0 + pq + 8 * i2;
      gx[(size_t)p * G3 + g] = acc[i2][u] + rl[pq + 8 * i2] * wxr + bxv;
    }
  }
}

// ---------------- K5: GRU (one wave per row) + fused segment atomics ----------------
__global__ __launch_bounds__(256) void k_gru(const float* __restrict__ gx,
                                             const float* __restrict__ WhT4,
                                             const float* __restrict__ bh,
                                             const int* __restrict__ items,
                                             float* __restrict__ sums,
                                             float* __restrict__ counts,
                                             float* __restrict__ hT) {
  __shared__ float h[4][DD];
  int t = threadIdx.x;
  int r = t >> 6, w = t & 63;
  int b = blockIdx.x * 4 + r;
  h[r][w] = 0.f; h[r][w + 64] = 0.f;
  float bhv[6];
#pragma unroll
  for (int u = 0; u < 6; ++u) bhv[u] = bh[w + 64 * u];
  const float* gxb = gx + (size_t)b * SS * G3;
  float h0 = 0.f, h1 = 0.f;
  __syncthreads();
  for (int s = 0; s < SS; ++s) {
    float acc[6] = {0.f, 0.f, 0.f, 0.f, 0.f, 0.f};
    for (int k4 = 0; k4 < 32; ++k4) {
      f32x4 hv = *(f32x4*)&h[r][k4 * 4];
#pragma unroll
      for (int u = 0; u < 6; ++u) {
        f32x4 wv = *(const f32x4*)(WhT4 + ((size_t)(k4 * G3) + w + 64 * u) * 4);
        acc[u] += hv.x * wv.x + hv.y * wv.y + hv.z * wv.z + hv.w * wv.w;
      }
    }
    float r0 = sigf(gxb[s * G3 + w]            + acc[0] + bhv[0]);
    float r1 = sigf(gxb[s * G3 + w + 64]       + acc[1] + bhv[1]);
    float z0 = sigf(gxb[s * G3 + 128 + w]      + acc[2] + bhv[2]);
    float z1 = sigf(gxb[s * G3 + 128 + w + 64] + acc[3] + bhv[3]);
    float n0 = tanhf(gxb[s * G3 + 256 + w]      + r0 * (acc[4] + bhv[4]));
    float n1 = tanhf(gxb[s * G3 + 256 + w + 64] + r1 * (acc[5] + bhv[5]));
    h0 = (1.f - z0) * n0 + z0 * h0;
    h1 = (1.f - z1) * n1 + z1 * h1;
    __syncthreads();
    h[r][w] = h0; h[r][w + 64] = h1;
    __syncthreads();
    int it = items[b * SS + s];
    atomicAdd(sums + (size_t)it * DD + w, h0);
    atomicAdd(sums + (size_t)it * DD + w + 64, h1);
    if (w == 0) atomicAdd(counts + it, 1.f);
  }
  hT[b * DD + w] = h0;
  hT[b * DD + w + 64] = h1;
}

// ---------------- K6: items_input (bf16) ----------------
__global__ __launch_bounds__(256) void k_items(const float* __restrict__ table,
                                               const float* __restrict__ mem,
                                               const float* __restrict__ sums,
                                               const float* __restrict__ counts,
                                               unsigned short* __restrict__ Ibf) {
  size_t tid = (size_t)blockIdx.x * 256 + threadIdx.x;
  size_t i = tid >> 5; int c = (int)(tid & 31);
  if (i >= NII) return;
  float cnt = counts[i];
  size_t base = i * DD + c * 4;
  f32x4 m  = *(const f32x4*)(mem + base);
  f32x4 tb = *(const f32x4*)(table + base);
  float vx, vy, vz, vw;
  if (cnt > 0.f) {
    f32x4 sm = *(const f32x4*)(sums + base);
    vx = 0.5f * (m.x + sm.x / cnt) + tb.x;
    vy = 0.5f * (m.y + sm.y / cnt) + tb.y;
    vz = 0.5f * (m.z + sm.z / cnt) + tb.z;
    vw = 0.5f * (m.w + sm.w / cnt) + tb.w;
  } else {
    vx = m.x + tb.x; vy = m.y + tb.y; vz = m.z + tb.z; vw = m.w + tb.w;
  }
  unsigned long long pack = (unsigned long long)f2bf(vx)
                          | ((unsigned long long)f2bf(vy) << 16)
                          | ((unsigned long long)f2bf(vz) << 32)
                          | ((unsigned long long)f2bf(vw) << 48);
  *(unsigned long long*)(Ibf + base) = pack;
}

// ---------------- K7: rep (last-write-wins) + U' = hT[rep] @ M  -> bf16 ----------------
__global__ __launch_bounds__(256) void k_uprime(const int* __restrict__ ids,
                                                const float* __restrict__ hT,
                                                const float* __restrict__ M,
                                                unsigned short* __restrict__ Ubf) {
  __shared__ int   idsl[BB];
  __shared__ int   repl[16][16];
  __shared__ float hTl[16][DD];
  int t = threadIdx.x;
  for (int i = t; i < BB; i += 256) idsl[i] = ids[i];
  __syncthreads();
  int b0 = blockIdx.x * 16;
  int p = t >> 4, c = t & 15;
  int myid = idsl[b0 + p];
  int best = -1;
  for (int j = c * 64; j < c * 64 + 64; ++j)
    if (idsl[j] == myid) best = j;
  repl[p][c] = best;
  __syncthreads();
  if (c == 0) {
    int rr = -1;
#pragma unroll
    for (int q = 0; q < 16; ++q) rr = max(rr, repl[p][q]);
    repl[p][0] = rr;
  }
  __syncthreads();
  for (int i = t; i < 16 * 32; i += 256) {
    int rr = i >> 5, c4 = i & 31;
    int src = repl[rr][0];
    *(f32x4*)&hTl[rr][c4 * 4] = *(const f32x4*)(hT + (size_t)src * DD + c4 * 4);
  }
  __syncthreads();
  float acc[8] = {0.f, 0.f, 0.f, 0.f, 0.f, 0.f, 0.f, 0.f};
  for (int k1 = 0; k1 < DD; ++k1) {
    float hv = hTl[p][k1];
#pragma unroll
    for (int u = 0; u < 8; ++u)
      acc[u] = fmaf(hv, M[k1 * DD + c + 16 * u], acc[u]);
  }
#pragma unroll
  for (int u = 0; u < 8; ++u)
    Ubf[(size_t)(b0 + p) * DD + c + 16 * u] = f2bf(acc[u]);
}

// ---------------- K8: out = U' @ I^T  (bf16 MFMA, 64x64 block tile) ----------------
__device__ __forceinline__ bf16x8 bzero8() {
  bf16x8 z;
#pragma unroll
  for (int e = 0; e < 8; ++e) z[e] = (__bf16)0.f;
  return z;
}

__global__ __launch_bounds__(256) void k_gemm(const unsigned short* __restrict__ Ubf,
                                              const unsigned short* __restrict__ Ibf,
                                              float* __restrict__ out) {
  int bid = blockIdx.x;
  int bt = bid & 15, jt = bid >> 4;
  int b0 = bt * 64, j0 = jt * 64;
  int t = threadIdx.x;
  int wv = t >> 6, l = t & 63;
  int wr = wv >> 1, wc = wv & 1;
  int bw = b0 + wr * 32, jw = j0 + wc * 32;
  int lr = l & 15, lk = l >> 4;              // row-in-16, k-group-of-8
  f32x4 acc[2][2];
#pragma unroll
  for (int mi = 0; mi < 2; ++mi)
#pragma unroll
    for (int nj = 0; nj < 2; ++nj) { f32x4 z = {0.f,0.f,0.f,0.f}; acc[mi][nj] = z; }

#pragma unroll
  for (int kk = 0; kk < 4; ++kk) {
    int k0 = kk * 32 + lk * 8;
    bf16x8 a0 = *(const bf16x8*)(Ubf + (size_t)(bw + lr) * DD + k0);
    bf16x8 a1 = *(const bf16x8*)(Ubf + (size_t)(bw + 16 + lr) * DD + k0);
    int j0l = jw + lr, j1l = jw + 16 + lr;
    bf16x8 bv0, bv1;
    if (j0l < NII) bv0 = *(const bf16x8*)(Ibf + (size_t)j0l * DD + k0); else bv0 = bzero8();
    if (j1l < NII) bv1 = *(const bf16x8*)(Ibf + (size_t)j1l * DD + k0); else bv1 = bzero8();
    acc[0][0] = __builtin_amdgcn_mfma_f32_16x16x32_bf16(a0, bv0, acc[0][0], 0, 0, 0);
    acc[0][1] = __builtin_amdgcn_mfma_f32_16x16x32_bf16(a0, bv1, acc[0][1], 0, 0, 0);
    acc[1][0] = __builtin_amdgcn_mfma_f32_16x16x32_bf16(a1, bv0, acc[1][0], 0, 0, 0);
    acc[1][1] = __builtin_amdgcn_mfma_f32_16x16x32_bf16(a1, bv1, acc[1][1], 0, 0, 0);
  }
  // C/D layout: col = lane&15, row = (lane>>4)*4 + reg
#pragma unroll
  for (int mi = 0; mi < 2; ++mi) {
    int brow = bw + mi * 16 + lk * 4;
#pragma unroll
    for (int nj = 0; nj < 2; ++nj) {
      int jcol = jw + nj * 16 + lr;
      if (jcol < NII) {
#pragma unroll
        for (int q = 0; q < 4; ++q)
          out[(size_t)(brow + q) * NII + jcol] = acc[mi][nj][q];
      }
    }
  }
}

extern "C" void kernel_launch(void* const* d_in, const int* in_sizes, int n_in,
                              void* d_out, int out_size, void* d_ws, size_t ws_size,
                              hipStream_t stream) {
  const int*   users_ids   = (const int*)  d_in[0];
  const int*   users_items = (const int*)  d_in[1];
  const float* users_rew   = (const float*)d_in[2];
  const float* items_table = (const float*)d_in[4];
  const float* items_mem   = (const float*)d_in[6];
  const float* Wx  = (const float*)d_in[7];
  const float* Wh  = (const float*)d_in[8];
  const float* bx  = (const float*)d_in[9];
  const float* bh  = (const float*)d_in[10];
  const float* W_u = (const float*)d_in[11];
  const float* W_i = (const float*)d_in[12];
  float* out = (float*)d_out;
  (void)in_sizes; (void)n_in; (void)out_size; (void)ws_size;

  char* ws = (char*)d_ws;
  size_t off = 0;
  auto alloc = [&](size_t bytes) {
    void* p = ws + off;
    off = (off + bytes + 255) & ~(size_t)255;
    return p;
  };
  float* sums   = (float*)alloc(sizeof(float) * (size_t)NII * DD);
  float* counts = (float*)alloc(sizeof(float) * NII);
  float* gx     = (float*)alloc(sizeof(float) * (size_t)BB * SS * G3);
  float* WhT4   = (float*)alloc(sizeof(float) * G3 * DD);
  float* M      = (float*)alloc(sizeof(float) * DD * DD);
  float* hT     = (float*)alloc(sizeof(float) * BB * DD);
  unsigned short* Ubf = (unsigned short*)alloc(sizeof(unsigned short) * BB * DD);
  unsigned short* Ibf = (unsigned short*)alloc(sizeof(unsigned short) * (size_t)NII * DD);

  hipLaunchKernelGGL(k_zero_seg, dim3((BB * SS * 32) / 256), dim3(256), 0, stream,
                     users_items, sums, counts);
  hipLaunchKernelGGL(k_whT4, dim3((G3 * 32) / 256), dim3(256), 0, stream, Wh, WhT4);
  hipLaunchKernelGGL(k_M, dim3(64), dim3(256), 0, stream, W_u, W_i, M);
  hipLaunchKernelGGL(k_gx, dim3((BB * SS / 16) * 4), dim3(256), 0, stream,
                     users_items, users_rew, items_table, Wx, bx, gx);
  hipLaunchKernelGGL(k_gru, dim3(BB / 4), dim3(256), 0, stream,
                     gx, WhT4, bh, users_items, sums, counts, hT);
  hipLaunchKernelGGL(k_items, dim3((NII * 32 + 255) / 256), dim3(256), 0, stream,
                     items_table, items_mem, sums, counts, Ibf);
  hipLaunchKernelGGL(k_uprime, dim3(BB / 16), dim3(256), 0, stream,
                     users_ids, hT, M, Ubf);
  hipLaunchKernelGGL(k_gemm, dim3(16 * ((NII + 63) / 64)), dim3(256), 0, stream,
                     Ubf, Ibf, out);
}

// Round 2
// 426.108 us; speedup vs baseline: 2.5784x; 2.5784x over previous
//
#include <hip/hip_runtime.h>
#include <hip/hip_bf16.h>
#include <stdint.h>

#define BB  1024
#define SS  20
#define DD  128
#define G3  384      // 3*D
#define NII 100000
#define KXX 136      // D + R

typedef float  f32x4  __attribute__((ext_vector_type(4)));
typedef __bf16 bf16x8 __attribute__((ext_vector_type(8)));

__device__ __forceinline__ unsigned short f2bf(float x) {
  uint32_t u = __float_as_uint(x);
  uint32_t r = (u + 0x7fffu + ((u >> 16) & 1u)) >> 16;   // RNE
  return (unsigned short)r;
}

__device__ __forceinline__ float sigf(float x) { return 1.f / (1.f + expf(-x)); }

// ---------------- K1: zero sums/counts for touched items ----------------
__global__ __launch_bounds__(256) void k_zero_seg(const int* __restrict__ items,
                                                  float* __restrict__ sums,
                                                  float* __restrict__ counts) {
  int tid = blockIdx.x * 256 + threadIdx.x;
  int p = tid >> 5, c = tid & 31;
  if (p >= BB * SS) return;
  int it = items[p];
  f32x4 z = {0.f, 0.f, 0.f, 0.f};
  *(f32x4*)(sums + (size_t)it * DD + c * 4) = z;
  if (c == 0) counts[it] = 0.f;
}

// ---------------- K3: M = W_u @ W_i^T  (128x128) ----------------
__global__ __launch_bounds__(256) void k_M(const float* __restrict__ Wu,
                                           const float* __restrict__ Wi,
                                           float* __restrict__ M) {
  int idx = blockIdx.x * 256 + threadIdx.x;  // 16384 total
  int k1 = idx >> 7, k2 = idx & 127;
  float acc = 0.f;
  for (int e = 0; e < DD; ++e)
    acc = fmaf(Wu[k1 * DD + e], Wi[k2 * DD + e], acc);
  M[idx] = acc;
}

// ---------------- K4: gx[p][g] = x[p] . Wx[g] + bx[g] ----------------
__global__ __launch_bounds__(256) void k_gx(const int* __restrict__ items,
                                            const float* __restrict__ rew,
                                            const float* __restrict__ table,
                                            const float* __restrict__ Wx,
                                            const float* __restrict__ bx,
                                            float* __restrict__ gx) {
  __shared__ float Wl[96][140];
  __shared__ float Al[16][128];
  __shared__ float rl[16];
  int gt = blockIdx.x & 3, pt = blockIdx.x >> 2;
  int g0 = gt * 96, p0 = pt * 16;
  int t = threadIdx.x;
  for (int i = t; i < 96 * 34; i += 256) {           // 136 cols = 34 float4
    int r = i / 34, c = i % 34;
    f32x4 v = *(const f32x4*)(Wx + (size_t)(g0 + r) * KXX + c * 4);
    *(f32x4*)&Wl[r][c * 4] = v;
  }
  for (int i = t; i < 16 * 32; i += 256) {
    int r = i >> 5, c = i & 31;
    int it = items[p0 + r];
    *(f32x4*)&Al[r][c * 4] = *(const f32x4*)(table + (size_t)it * DD + c * 4);
  }
  if (t < 16) rl[t] = rew[p0 + t];
  __syncthreads();

  int tg = t & 31, pq = (t >> 5) & 7;
  float acc[2][3] = {};
  for (int k4 = 0; k4 < 32; ++k4) {
    f32x4 a0 = *(f32x4*)&Al[pq][k4 * 4];
    f32x4 a1 = *(f32x4*)&Al[pq + 8][k4 * 4];
#pragma unroll
    for (int u = 0; u < 3; ++u) {
      f32x4 w = *(f32x4*)&Wl[tg + 32 * u][k4 * 4];
      acc[0][u] += a0.x * w.x + a0.y * w.y + a0.z * w.z + a0.w * w.w;
      acc[1][u] += a1.x * w.x + a1.y * w.y + a1.z * w.z + a1.w * w.w;
    }
  }
#pragma unroll
  for (int u = 0; u < 3; ++u) {
    int gl = tg + 32 * u, g = g0 + gl;
    float wxr = 0.f;
#pragma unroll
    for (int q = 0; q < 8; ++q) wxr += Wl[gl][128 + q];
    float bxv = bx[g];
#pragma unroll
    for (int i2 = 0; i2 < 2; ++i2) {
      int p = p0 + pq + 8 * i2;
      gx[(size_t)p * G3 + g] = acc[i2][u] + rl[pq + 8 * i2] * wxr + bxv;
    }
  }
}

// ---------------- K5: GRU with register-resident Wh ----------------
// Block = 256 threads (4 waves) = 4 rows. Lane gl holds Wh[g = tt*128 + gl/2]
// cols [half*64, half*64+64) for tt=0..2 -> 192 VGPRs; Wh is read from HBM once.
__global__ __launch_bounds__(256, 1) void k_gru(const float* __restrict__ gx,
                                                const float* __restrict__ Wh,
                                                const float* __restrict__ bh,
                                                const int* __restrict__ items,
                                                float* __restrict__ sums,
                                                float* __restrict__ counts,
                                                float* __restrict__ hT) {
  __shared__ float hl[4][DD];    // h per row
  __shared__ float ghl[4][G3];   // Wh @ h per row
  int t = threadIdx.x;
  int u = t >> 6, w = t & 63;          // wave, lane
  int gbase = t >> 1, half = t & 1;    // g within gate-block, k-half

  f32x4 wreg[3][16];
#pragma unroll
  for (int tt = 0; tt < 3; ++tt) {
    const float* src = Wh + (size_t)(tt * 128 + gbase) * DD + half * 64;
#pragma unroll
    for (int j4 = 0; j4 < 16; ++j4)
      wreg[tt][j4] = *(const f32x4*)(src + j4 * 4);
  }
  float bh6[6];
#pragma unroll
  for (int q = 0; q < 6; ++q) bh6[q] = bh[w + 64 * q];

  int b = blockIdx.x * 4 + u;
  const float* gxb = gx + (size_t)b * SS * G3;
  hl[u][w] = 0.f; hl[u][w + 64] = 0.f;
  float h0 = 0.f, h1 = 0.f;
  __syncthreads();

  for (int s = 0; s < SS; ++s) {
    // phase 1: all lanes compute gh partials for all 4 rows
#pragma unroll
    for (int r = 0; r < 4; ++r) {
      float a0 = 0.f, a1 = 0.f, a2 = 0.f;
#pragma unroll
      for (int j4 = 0; j4 < 16; ++j4) {
        f32x4 hv = *(f32x4*)&hl[r][half * 64 + j4 * 4];
        a0 += wreg[0][j4].x * hv.x + wreg[0][j4].y * hv.y
            + wreg[0][j4].z * hv.z + wreg[0][j4].w * hv.w;
        a1 += wreg[1][j4].x * hv.x + wreg[1][j4].y * hv.y
            + wreg[1][j4].z * hv.z + wreg[1][j4].w * hv.w;
        a2 += wreg[2][j4].x * hv.x + wreg[2][j4].y * hv.y
            + wreg[2][j4].z * hv.z + wreg[2][j4].w * hv.w;
      }
      a0 += __shfl_xor(a0, 1);
      a1 += __shfl_xor(a1, 1);
      a2 += __shfl_xor(a2, 1);
      if (!half) {
        ghl[r][gbase]       = a0;
        ghl[r][128 + gbase] = a1;
        ghl[r][256 + gbase] = a2;
      }
    }
    __syncthreads();
    // phase 2: wave u updates row u's gates/state
    float gr0 = ghl[u][w]       + bh6[0];
    float gr1 = ghl[u][w + 64]  + bh6[1];
    float gz0 = ghl[u][128 + w] + bh6[2];
    float gz1 = ghl[u][192 + w] + bh6[3];
    float gn0 = ghl[u][256 + w] + bh6[4];
    float gn1 = ghl[u][320 + w] + bh6[5];
    float r0 = sigf(gxb[s * G3 + w]       + gr0);
    float r1 = sigf(gxb[s * G3 + 64 + w]  + gr1);
    float z0 = sigf(gxb[s * G3 + 128 + w] + gz0);
    float z1 = sigf(gxb[s * G3 + 192 + w] + gz1);
    float n0 = tanhf(gxb[s * G3 + 256 + w] + r0 * gn0);
    float n1 = tanhf(gxb[s * G3 + 320 + w] + r1 * gn1);
    h0 = (1.f - z0) * n0 + z0 * h0;
    h1 = (1.f - z1) * n1 + z1 * h1;
    hl[u][w] = h0; hl[u][w + 64] = h1;
    int it = items[b * SS + s];
    atomicAdd(sums + (size_t)it * DD + w, h0);
    atomicAdd(sums + (size_t)it * DD + w + 64, h1);
    if (w == 0) atomicAdd(counts + it, 1.f);
    __syncthreads();
  }
  hT[b * DD + w] = h0;
  hT[b * DD + w + 64] = h1;
}

// ---------------- K6: items_input (bf16) ----------------
__global__ __launch_bounds__(256) void k_items(const float* __restrict__ table,
                                               const float* __restrict__ mem,
                                               const float* __restrict__ sums,
                                               const float* __restrict__ counts,
                                               unsigned short* __restrict__ Ibf) {
  size_t tid = (size_t)blockIdx.x * 256 + threadIdx.x;
  size_t i = tid >> 5; int c = (int)(tid & 31);
  if (i >= NII) return;
  float cnt = counts[i];
  size_t base = i * DD + c * 4;
  f32x4 m  = *(const f32x4*)(mem + base);
  f32x4 tb = *(const f32x4*)(table + base);
  float vx, vy, vz, vw;
  if (cnt > 0.f) {
    f32x4 sm = *(const f32x4*)(sums + base);
    vx = 0.5f * (m.x + sm.x / cnt) + tb.x;
    vy = 0.5f * (m.y + sm.y / cnt) + tb.y;
    vz = 0.5f * (m.z + sm.z / cnt) + tb.z;
    vw = 0.5f * (m.w + sm.w / cnt) + tb.w;
  } else {
    vx = m.x + tb.x; vy = m.y + tb.y; vz = m.z + tb.z; vw = m.w + tb.w;
  }
  unsigned long long pack = (unsigned long long)f2bf(vx)
                          | ((unsigned long long)f2bf(vy) << 16)
                          | ((unsigned long long)f2bf(vz) << 32)
                          | ((unsigned long long)f2bf(vw) << 48);
  *(unsigned long long*)(Ibf + base) = pack;
}

// ---------------- K7: rep (last-write-wins) + U' = hT[rep] @ M  -> bf16 ----------------
__global__ __launch_bounds__(256) void k_uprime(const int* __restrict__ ids,
                                                const float* __restrict__ hT,
                                                const float* __restrict__ M,
                                                unsigned short* __restrict__ Ubf) {
  __shared__ int   idsl[BB];
  __shared__ int   repl[16][16];
  __shared__ float hTl[16][DD];
  int t = threadIdx.x;
  for (int i = t; i < BB; i += 256) idsl[i] = ids[i];
  __syncthreads();
  int b0 = blockIdx.x * 16;
  int p = t >> 4, c = t & 15;
  int myid = idsl[b0 + p];
  int best = -1;
  for (int j = c * 64; j < c * 64 + 64; ++j)
    if (idsl[j] == myid) best = j;
  repl[p][c] = best;
  __syncthreads();
  if (c == 0) {
    int rr = -1;
#pragma unroll
    for (int q = 0; q < 16; ++q) rr = max(rr, repl[p][q]);
    repl[p][0] = rr;
  }
  __syncthreads();
  for (int i = t; i < 16 * 32; i += 256) {
    int rr = i >> 5, c4 = i & 31;
    int src = repl[rr][0];
    *(f32x4*)&hTl[rr][c4 * 4] = *(const f32x4*)(hT + (size_t)src * DD + c4 * 4);
  }
  __syncthreads();
  float acc[8] = {0.f, 0.f, 0.f, 0.f, 0.f, 0.f, 0.f, 0.f};
  for (int k1 = 0; k1 < DD; ++k1) {
    float hv = hTl[p][k1];
#pragma unroll
    for (int u = 0; u < 8; ++u)
      acc[u] = fmaf(hv, M[k1 * DD + c + 16 * u], acc[u]);
  }
#pragma unroll
  for (int u = 0; u < 8; ++u)
    Ubf[(size_t)(b0 + p) * DD + c + 16 * u] = f2bf(acc[u]);
}

// ---------------- K8: out = U' @ I^T  (bf16 MFMA, 64x64 block tile) ----------------
__device__ __forceinline__ bf16x8 bzero8() {
  bf16x8 z;
#pragma unroll
  for (int e = 0; e < 8; ++e) z[e] = (__bf16)0.f;
  return z;
}

__global__ __launch_bounds__(256) void k_gemm(const unsigned short* __restrict__ Ubf,
                                              const unsigned short* __restrict__ Ibf,
                                              float* __restrict__ out) {
  int bid = blockIdx.x;
  int bt = bid & 15, jt = bid >> 4;
  int b0 = bt * 64, j0 = jt * 64;
  int t = threadIdx.x;
  int wv = t >> 6, l = t & 63;
  int wr = wv >> 1, wc = wv & 1;
  int bw = b0 + wr * 32, jw = j0 + wc * 32;
  int lr = l & 15, lk = l >> 4;              // row-in-16, k-group-of-8
  f32x4 acc[2][2];
#pragma unroll
  for (int mi = 0; mi < 2; ++mi)
#pragma unroll
    for (int nj = 0; nj < 2; ++nj) { f32x4 z = {0.f,0.f,0.f,0.f}; acc[mi][nj] = z; }

#pragma unroll
  for (int kk = 0; kk < 4; ++kk) {
    int k0 = kk * 32 + lk * 8;
    bf16x8 a0 = *(const bf16x8*)(Ubf + (size_t)(bw + lr) * DD + k0);
    bf16x8 a1 = *(const bf16x8*)(Ubf + (size_t)(bw + 16 + lr) * DD + k0);
    int j0l = jw + lr, j1l = jw + 16 + lr;
    bf16x8 bv0, bv1;
    if (j0l < NII) bv0 = *(const bf16x8*)(Ibf + (size_t)j0l * DD + k0); else bv0 = bzero8();
    if (j1l < NII) bv1 = *(const bf16x8*)(Ibf + (size_t)j1l * DD + k0); else bv1 = bzero8();
    acc[0][0] = __builtin_amdgcn_mfma_f32_16x16x32_bf16(a0, bv0, acc[0][0], 0, 0, 0);
    acc[0][1] = __builtin_amdgcn_mfma_f32_16x16x32_bf16(a0, bv1, acc[0][1], 0, 0, 0);
    acc[1][0] = __builtin_amdgcn_mfma_f32_16x16x32_bf16(a1, bv0, acc[1][0], 0, 0, 0);
    acc[1][1] = __builtin_amdgcn_mfma_f32_16x16x32_bf16(a1, bv1, acc[1][1], 0, 0, 0);
  }
  // C/D layout: col = lane&15, row = (lane>>4)*4 + reg
#pragma unroll
  for (int mi = 0; mi < 2; ++mi) {
    int brow = bw + mi * 16 + lk * 4;
#pragma unroll
    for (int nj = 0; nj < 2; ++nj) {
      int jcol = jw + nj * 16 + lr;
      if (jcol < NII) {
#pragma unroll
        for (int q = 0; q < 4; ++q)
          out[(size_t)(brow + q) * NII + jcol] = acc[mi][nj][q];
      }
    }
  }
}

extern "C" void kernel_launch(void* const* d_in, const int* in_sizes, int n_in,
                              void* d_out, int out_size, void* d_ws, size_t ws_size,
                              hipStream_t stream) {
  const int*   users_ids   = (const int*)  d_in[0];
  const int*   users_items = (const int*)  d_in[1];
  const float* users_rew   = (const float*)d_in[2];
  const float* items_table = (const float*)d_in[4];
  const float* items_mem   = (const float*)d_in[6];
  const float* Wx  = (const float*)d_in[7];
  const float* Wh  = (const float*)d_in[8];
  const float* bx  = (const float*)d_in[9];
  const float* bh  = (const float*)d_in[10];
  const float* W_u = (const float*)d_in[11];
  const float* W_i = (const float*)d_in[12];
  float* out = (float*)d_out;
  (void)in_sizes; (void)n_in; (void)out_size; (void)ws_size;

  char* ws = (char*)d_ws;
  size_t off = 0;
  auto alloc = [&](size_t bytes) {
    void* p = ws + off;
    off = (off + bytes + 255) & ~(size_t)255;
    return p;
  };
  float* sums   = (float*)alloc(sizeof(float) * (size_t)NII * DD);
  float* counts = (float*)alloc(sizeof(float) * NII);
  float* gx     = (float*)alloc(sizeof(float) * (size_t)BB * SS * G3);
  float* M      = (float*)alloc(sizeof(float) * DD * DD);
  float* hT     = (float*)alloc(sizeof(float) * BB * DD);
  unsigned short* Ubf = (unsigned short*)alloc(sizeof(unsigned short) * BB * DD);
  unsigned short* Ibf = (unsigned short*)alloc(sizeof(unsigned short) * (size_t)NII * DD);

  hipLaunchKernelGGL(k_zero_seg, dim3((BB * SS * 32) / 256), dim3(256), 0, stream,
                     users_items, sums, counts);
  hipLaunchKernelGGL(k_M, dim3(64), dim3(256), 0, stream, W_u, W_i, M);
  hipLaunchKernelGGL(k_gx, dim3((BB * SS / 16) * 4), dim3(256), 0, stream,
                     users_items, users_rew, items_table, Wx, bx, gx);
  hipLaunchKernelGGL(k_gru, dim3(BB / 4), dim3(256), 0, stream,
                     gx, Wh, bh, users_items, sums, counts, hT);
  hipLaunchKernelGGL(k_items, dim3((NII * 32 + 255) / 256), dim3(256), 0, stream,
                     items_table, items_mem, sums, counts, Ibf);
  hipLaunchKernelGGL(k_uprime, dim3(BB / 16), dim3(256), 0, stream,
                     users_ids, hT, M, Ubf);
  hipLaunchKernelGGL(k_gemm, dim3(16 * ((NII + 63) / 64)), dim3(256), 0, stream,
                     Ubf, Ibf, out);
}

// Round 3
// 370.221 us; speedup vs baseline: 2.9676x; 1.1510x over previous
//
#include <hip/hip_runtime.h>
#include <hip/hip_bf16.h>
#include <stdint.h>

#define BB  1024
#define SS  20
#define DD  128
#define G3  384      // 3*D
#define NII 100000
#define KXX 136      // D + R

typedef float  f32x4  __attribute__((ext_vector_type(4)));
typedef __bf16 bf16x8 __attribute__((ext_vector_type(8)));

__device__ __forceinline__ unsigned short f2bf(float x) {
  uint32_t u = __float_as_uint(x);
  uint32_t r = (u + 0x7fffu + ((u >> 16) & 1u)) >> 16;   // RNE
  return (unsigned short)r;
}

__device__ __forceinline__ float sigf(float x) { return 1.f / (1.f + expf(-x)); }

// ---------------- K1: zero sums/counts for touched items ----------------
__global__ __launch_bounds__(256) void k_zero_seg(const int* __restrict__ items,
                                                  float* __restrict__ sums,
                                                  float* __restrict__ counts) {
  int tid = blockIdx.x * 256 + threadIdx.x;
  int p = tid >> 5, c = tid & 31;
  if (p >= BB * SS) return;
  int it = items[p];
  f32x4 z = {0.f, 0.f, 0.f, 0.f};
  *(f32x4*)(sums + (size_t)it * DD + c * 4) = z;
  if (c == 0) counts[it] = 0.f;
}

// ---------------- K3: M = W_u @ W_i^T  (128x128) ----------------
__global__ __launch_bounds__(256) void k_M(const float* __restrict__ Wu,
                                           const float* __restrict__ Wi,
                                           float* __restrict__ M) {
  int idx = blockIdx.x * 256 + threadIdx.x;  // 16384 total
  int k1 = idx >> 7, k2 = idx & 127;
  float acc = 0.f;
  for (int e = 0; e < DD; ++e)
    acc = fmaf(Wu[k1 * DD + e], Wi[k2 * DD + e], acc);
  M[idx] = acc;
}

// ---------------- K4: gx[p][g] = x[p] . Wx[g] + bx[g] ----------------
__global__ __launch_bounds__(256) void k_gx(const int* __restrict__ items,
                                            const float* __restrict__ rew,
                                            const float* __restrict__ table,
                                            const float* __restrict__ Wx,
                                            const float* __restrict__ bx,
                                            float* __restrict__ gx) {
  __shared__ float Wl[96][140];
  __shared__ float Al[16][128];
  __shared__ float rl[16];
  int gt = blockIdx.x & 3, pt = blockIdx.x >> 2;
  int g0 = gt * 96, p0 = pt * 16;
  int t = threadIdx.x;
  for (int i = t; i < 96 * 34; i += 256) {           // 136 cols = 34 float4
    int r = i / 34, c = i % 34;
    f32x4 v = *(const f32x4*)(Wx + (size_t)(g0 + r) * KXX + c * 4);
    *(f32x4*)&Wl[r][c * 4] = v;
  }
  for (int i = t; i < 16 * 32; i += 256) {
    int r = i >> 5, c = i & 31;
    int it = items[p0 + r];
    *(f32x4*)&Al[r][c * 4] = *(const f32x4*)(table + (size_t)it * DD + c * 4);
  }
  if (t < 16) rl[t] = rew[p0 + t];
  __syncthreads();

  int tg = t & 31, pq = (t >> 5) & 7;
  float acc[2][3] = {};
  for (int k4 = 0; k4 < 32; ++k4) {
    f32x4 a0 = *(f32x4*)&Al[pq][k4 * 4];
    f32x4 a1 = *(f32x4*)&Al[pq + 8][k4 * 4];
#pragma unroll
    for (int u = 0; u < 3; ++u) {
      f32x4 w = *(f32x4*)&Wl[tg + 32 * u][k4 * 4];
      acc[0][u] += a0.x * w.x + a0.y * w.y + a0.z * w.z + a0.w * w.w;
      acc[1][u] += a1.x * w.x + a1.y * w.y + a1.z * w.z + a1.w * w.w;
    }
  }
#pragma unroll
  for (int u = 0; u < 3; ++u) {
    int gl = tg + 32 * u, g = g0 + gl;
    float wxr = 0.f;
#pragma unroll
    for (int q = 0; q < 8; ++q) wxr += Wl[gl][128 + q];
    float bxv = bx[g];
#pragma unroll
    for (int i2 = 0; i2 < 2; ++i2) {
      int p = p0 + pq + 8 * i2;
      gx[(size_t)p * G3 + g] = acc[i2][u] + rl[pq + 8 * i2] * wxr + bxv;
    }
  }
}

// ---------------- K5: GRU with register-resident Wh ----------------
__global__ __launch_bounds__(256, 1) void k_gru(const float* __restrict__ gx,
                                                const float* __restrict__ Wh,
                                                const float* __restrict__ bh,
                                                const int* __restrict__ items,
                                                float* __restrict__ sums,
                                                float* __restrict__ counts,
                                                float* __restrict__ hT) {
  __shared__ float hl[4][DD];    // h per row
  __shared__ float ghl[4][G3];   // Wh @ h per row
  int t = threadIdx.x;
  int u = t >> 6, w = t & 63;          // wave, lane
  int gbase = t >> 1, half = t & 1;    // g within gate-block, k-half

  f32x4 wreg[3][16];
#pragma unroll
  for (int tt = 0; tt < 3; ++tt) {
    const float* src = Wh + (size_t)(tt * 128 + gbase) * DD + half * 64;
#pragma unroll
    for (int j4 = 0; j4 < 16; ++j4)
      wreg[tt][j4] = *(const f32x4*)(src + j4 * 4);
  }
  float bh6[6];
#pragma unroll
  for (int q = 0; q < 6; ++q) bh6[q] = bh[w + 64 * q];

  int b = blockIdx.x * 4 + u;
  const float* gxb = gx + (size_t)b * SS * G3;
  hl[u][w] = 0.f; hl[u][w + 64] = 0.f;
  float h0 = 0.f, h1 = 0.f;
  __syncthreads();

  for (int s = 0; s < SS; ++s) {
    // phase 1: all lanes compute gh partials for all 4 rows
#pragma unroll
    for (int r = 0; r < 4; ++r) {
      float a0 = 0.f, a1 = 0.f, a2 = 0.f;
#pragma unroll
      for (int j4 = 0; j4 < 16; ++j4) {
        f32x4 hv = *(f32x4*)&hl[r][half * 64 + j4 * 4];
        a0 += wreg[0][j4].x * hv.x + wreg[0][j4].y * hv.y
            + wreg[0][j4].z * hv.z + wreg[0][j4].w * hv.w;
        a1 += wreg[1][j4].x * hv.x + wreg[1][j4].y * hv.y
            + wreg[1][j4].z * hv.z + wreg[1][j4].w * hv.w;
        a2 += wreg[2][j4].x * hv.x + wreg[2][j4].y * hv.y
            + wreg[2][j4].z * hv.z + wreg[2][j4].w * hv.w;
      }
      a0 += __shfl_xor(a0, 1);
      a1 += __shfl_xor(a1, 1);
      a2 += __shfl_xor(a2, 1);
      if (!half) {
        ghl[r][gbase]       = a0;
        ghl[r][128 + gbase] = a1;
        ghl[r][256 + gbase] = a2;
      }
    }
    __syncthreads();
    // phase 2: wave u updates row u's gates/state
    float gr0 = ghl[u][w]       + bh6[0];
    float gr1 = ghl[u][w + 64]  + bh6[1];
    float gz0 = ghl[u][128 + w] + bh6[2];
    float gz1 = ghl[u][192 + w] + bh6[3];
    float gn0 = ghl[u][256 + w] + bh6[4];
    float gn1 = ghl[u][320 + w] + bh6[5];
    float r0 = sigf(gxb[s * G3 + w]       + gr0);
    float r1 = sigf(gxb[s * G3 + 64 + w]  + gr1);
    float z0 = sigf(gxb[s * G3 + 128 + w] + gz0);
    float z1 = sigf(gxb[s * G3 + 192 + w] + gz1);
    float n0 = tanhf(gxb[s * G3 + 256 + w] + r0 * gn0);
    float n1 = tanhf(gxb[s * G3 + 320 + w] + r1 * gn1);
    h0 = (1.f - z0) * n0 + z0 * h0;
    h1 = (1.f - z1) * n1 + z1 * h1;
    hl[u][w] = h0; hl[u][w + 64] = h1;
    int it = items[b * SS + s];
    atomicAdd(sums + (size_t)it * DD + w, h0);
    atomicAdd(sums + (size_t)it * DD + w + 64, h1);
    if (w == 0) atomicAdd(counts + it, 1.f);
    __syncthreads();
  }
  hT[b * DD + w] = h0;
  hT[b * DD + w + 64] = h1;
}

// ---------------- K6: items_input (bf16) ----------------
__global__ __launch_bounds__(256) void k_items(const float* __restrict__ table,
                                               const float* __restrict__ mem,
                                               const float* __restrict__ sums,
                                               const float* __restrict__ counts,
                                               unsigned short* __restrict__ Ibf) {
  size_t tid = (size_t)blockIdx.x * 256 + threadIdx.x;
  size_t i = tid >> 5; int c = (int)(tid & 31);
  if (i >= NII) return;
  float cnt = counts[i];
  size_t base = i * DD + c * 4;
  f32x4 m  = *(const f32x4*)(mem + base);
  f32x4 tb = *(const f32x4*)(table + base);
  float vx, vy, vz, vw;
  if (cnt > 0.f) {
    f32x4 sm = *(const f32x4*)(sums + base);
    vx = 0.5f * (m.x + sm.x / cnt) + tb.x;
    vy = 0.5f * (m.y + sm.y / cnt) + tb.y;
    vz = 0.5f * (m.z + sm.z / cnt) + tb.z;
    vw = 0.5f * (m.w + sm.w / cnt) + tb.w;
  } else {
    vx = m.x + tb.x; vy = m.y + tb.y; vz = m.z + tb.z; vw = m.w + tb.w;
  }
  unsigned long long pack = (unsigned long long)f2bf(vx)
                          | ((unsigned long long)f2bf(vy) << 16)
                          | ((unsigned long long)f2bf(vz) << 32)
                          | ((unsigned long long)f2bf(vw) << 48);
  *(unsigned long long*)(Ibf + base) = pack;
}

// ---------------- K7: rep (last-write-wins) + U' = hT[rep] @ M  -> bf16 ----------------
__global__ __launch_bounds__(256) void k_uprime(const int* __restrict__ ids,
                                                const float* __restrict__ hT,
                                                const float* __restrict__ M,
                                                unsigned short* __restrict__ Ubf) {
  __shared__ int   idsl[BB];
  __shared__ int   repl[16][16];
  __shared__ float hTl[16][DD];
  int t = threadIdx.x;
  for (int i = t; i < BB; i += 256) idsl[i] = ids[i];
  __syncthreads();
  int b0 = blockIdx.x * 16;
  int p = t >> 4, c = t & 15;
  int myid = idsl[b0 + p];
  int best = -1;
  for (int j = c * 64; j < c * 64 + 64; ++j)
    if (idsl[j] == myid) best = j;
  repl[p][c] = best;
  __syncthreads();
  if (c == 0) {
    int rr = -1;
#pragma unroll
    for (int q = 0; q < 16; ++q) rr = max(rr, repl[p][q]);
    repl[p][0] = rr;
  }
  __syncthreads();
  for (int i = t; i < 16 * 32; i += 256) {
    int rr = i >> 5, c4 = i & 31;
    int src = repl[rr][0];
    *(f32x4*)&hTl[rr][c4 * 4] = *(const f32x4*)(hT + (size_t)src * DD + c4 * 4);
  }
  __syncthreads();
  float acc[8] = {0.f, 0.f, 0.f, 0.f, 0.f, 0.f, 0.f, 0.f};
  for (int k1 = 0; k1 < DD; ++k1) {
    float hv = hTl[p][k1];
#pragma unroll
    for (int u = 0; u < 8; ++u)
      acc[u] = fmaf(hv, M[k1 * DD + c + 16 * u], acc[u]);
  }
#pragma unroll
  for (int u = 0; u < 8; ++u)
    Ubf[(size_t)(b0 + p) * DD + c + 16 * u] = f2bf(acc[u]);
}

// ---------------- K8: out = U' @ I^T  (bf16 MFMA, j-strip persistent-B) ----------------
// One block owns a 64-wide j strip; B fragments live in registers across all
// 16 b-chunks -> Ibf read exactly once device-wide; Ubf (256 KB) is L2-resident.
__device__ __forceinline__ bf16x8 bzero8() {
  bf16x8 z;
#pragma unroll
  for (int e = 0; e < 8; ++e) z[e] = (__bf16)0.f;
  return z;
}

__global__ __launch_bounds__(256) void k_gemm(const unsigned short* __restrict__ Ubf,
                                              const unsigned short* __restrict__ Ibf,
                                              float* __restrict__ out) {
  int j0 = blockIdx.x * 64;
  int t = threadIdx.x;
  int wv = t >> 6, l = t & 63;
  int wr = wv >> 1, wc = wv & 1;           // wave's 32-row / 32-col quadrant
  int jw = j0 + wc * 32;
  int lr = l & 15, lk = l >> 4;            // row-in-16, k-group-of-8

  // Hoist B fragments: 8 x bf16x8 = 32 VGPRs, reused for all b-chunks
  bf16x8 bfrag[4][2];
  int j0l = jw + lr, j1l = jw + 16 + lr;
#pragma unroll
  for (int kk = 0; kk < 4; ++kk) {
    int k0 = kk * 32 + lk * 8;
    bfrag[kk][0] = (j0l < NII) ? *(const bf16x8*)(Ibf + (size_t)j0l * DD + k0) : bzero8();
    bfrag[kk][1] = (j1l < NII) ? *(const bf16x8*)(Ibf + (size_t)j1l * DD + k0) : bzero8();
  }

  for (int bc = 0; bc < 16; ++bc) {
    int bw = bc * 64 + wr * 32;
    f32x4 acc[2][2];
#pragma unroll
    for (int mi = 0; mi < 2; ++mi)
#pragma unroll
      for (int nj = 0; nj < 2; ++nj) { f32x4 z = {0.f,0.f,0.f,0.f}; acc[mi][nj] = z; }

#pragma unroll
    for (int kk = 0; kk < 4; ++kk) {
      int k0 = kk * 32 + lk * 8;
      bf16x8 a0 = *(const bf16x8*)(Ubf + (size_t)(bw + lr) * DD + k0);
      bf16x8 a1 = *(const bf16x8*)(Ubf + (size_t)(bw + 16 + lr) * DD + k0);
      acc[0][0] = __builtin_amdgcn_mfma_f32_16x16x32_bf16(a0, bfrag[kk][0], acc[0][0], 0, 0, 0);
      acc[0][1] = __builtin_amdgcn_mfma_f32_16x16x32_bf16(a0, bfrag[kk][1], acc[0][1], 0, 0, 0);
      acc[1][0] = __builtin_amdgcn_mfma_f32_16x16x32_bf16(a1, bfrag[kk][0], acc[1][0], 0, 0, 0);
      acc[1][1] = __builtin_amdgcn_mfma_f32_16x16x32_bf16(a1, bfrag[kk][1], acc[1][1], 0, 0, 0);
    }
    // C/D layout: col = lane&15, row = (lane>>4)*4 + reg
#pragma unroll
    for (int mi = 0; mi < 2; ++mi) {
      int brow = bw + mi * 16 + lk * 4;
#pragma unroll
      for (int nj = 0; nj < 2; ++nj) {
        int jcol = jw + nj * 16 + lr;
        if (jcol < NII) {
#pragma unroll
          for (int q = 0; q < 4; ++q)
            out[(size_t)(brow + q) * NII + jcol] = acc[mi][nj][q];
        }
      }
    }
  }
}

extern "C" void kernel_launch(void* const* d_in, const int* in_sizes, int n_in,
                              void* d_out, int out_size, void* d_ws, size_t ws_size,
                              hipStream_t stream) {
  const int*   users_ids   = (const int*)  d_in[0];
  const int*   users_items = (const int*)  d_in[1];
  const float* users_rew   = (const float*)d_in[2];
  const float* items_table = (const float*)d_in[4];
  const float* items_mem   = (const float*)d_in[6];
  const float* Wx  = (const float*)d_in[7];
  const float* Wh  = (const float*)d_in[8];
  const float* bx  = (const float*)d_in[9];
  const float* bh  = (const float*)d_in[10];
  const float* W_u = (const float*)d_in[11];
  const float* W_i = (const float*)d_in[12];
  float* out = (float*)d_out;
  (void)in_sizes; (void)n_in; (void)out_size; (void)ws_size;

  char* ws = (char*)d_ws;
  size_t off = 0;
  auto alloc = [&](size_t bytes) {
    void* p = ws + off;
    off = (off + bytes + 255) & ~(size_t)255;
    return p;
  };
  float* sums   = (float*)alloc(sizeof(float) * (size_t)NII * DD);
  float* counts = (float*)alloc(sizeof(float) * NII);
  float* gx     = (float*)alloc(sizeof(float) * (size_t)BB * SS * G3);
  float* M      = (float*)alloc(sizeof(float) * DD * DD);
  float* hT     = (float*)alloc(sizeof(float) * BB * DD);
  unsigned short* Ubf = (unsigned short*)alloc(sizeof(unsigned short) * BB * DD);
  unsigned short* Ibf = (unsigned short*)alloc(sizeof(unsigned short) * (size_t)NII * DD);

  hipLaunchKernelGGL(k_zero_seg, dim3((BB * SS * 32) / 256), dim3(256), 0, stream,
                     users_items, sums, counts);
  hipLaunchKernelGGL(k_M, dim3(64), dim3(256), 0, stream, W_u, W_i, M);
  hipLaunchKernelGGL(k_gx, dim3((BB * SS / 16) * 4), dim3(256), 0, stream,
                     users_items, users_rew, items_table, Wx, bx, gx);
  hipLaunchKernelGGL(k_gru, dim3(BB / 4), dim3(256), 0, stream,
                     gx, Wh, bh, users_items, sums, counts, hT);
  hipLaunchKernelGGL(k_items, dim3((NII * 32 + 255) / 256), dim3(256), 0, stream,
                     items_table, items_mem, sums, counts, Ibf);
  hipLaunchKernelGGL(k_uprime, dim3(BB / 16), dim3(256), 0, stream,
                     users_ids, hT, M, Ubf);
  hipLaunchKernelGGL(k_gemm, dim3((NII + 63) / 64), dim3(256), 0, stream,
                     Ubf, Ibf, out);
}

// Round 4
// 359.704 us; speedup vs baseline: 3.0544x; 1.0292x over previous
//
#include <hip/hip_runtime.h>
#include <hip/hip_bf16.h>
#include <stdint.h>

#define BB  1024
#define SS  20
#define DD  128
#define G3  384      // 3*D
#define NII 100000
#define KXX 136      // D + R

typedef float  f32x4  __attribute__((ext_vector_type(4)));
typedef __bf16 bf16x8 __attribute__((ext_vector_type(8)));

__device__ __forceinline__ unsigned short f2bf(float x) {
  uint32_t u = __float_as_uint(x);
  uint32_t r = (u + 0x7fffu + ((u >> 16) & 1u)) >> 16;   // RNE
  return (unsigned short)r;
}

__device__ __forceinline__ float sigf(float x) { return 1.f / (1.f + expf(-x)); }

// ---------------- K1: zero sums/counts for touched items ----------------
__global__ __launch_bounds__(256) void k_zero_seg(const int* __restrict__ items,
                                                  float* __restrict__ sums,
                                                  float* __restrict__ counts) {
  int tid = blockIdx.x * 256 + threadIdx.x;
  int p = tid >> 5, c = tid & 31;
  if (p >= BB * SS) return;
  int it = items[p];
  f32x4 z = {0.f, 0.f, 0.f, 0.f};
  *(f32x4*)(sums + (size_t)it * DD + c * 4) = z;
  if (c == 0) counts[it] = 0.f;
}

// ---------------- K3: M = W_u @ W_i^T  (128x128) ----------------
__global__ __launch_bounds__(256) void k_M(const float* __restrict__ Wu,
                                           const float* __restrict__ Wi,
                                           float* __restrict__ M) {
  int idx = blockIdx.x * 256 + threadIdx.x;  // 16384 total
  int k1 = idx >> 7, k2 = idx & 127;
  float acc = 0.f;
  for (int e = 0; e < DD; ++e)
    acc = fmaf(Wu[k1 * DD + e], Wi[k2 * DD + e], acc);
  M[idx] = acc;
}

// ---------------- K4: gx[p][g] = x[p] . Wx[g] + bx[g] ----------------
__global__ __launch_bounds__(256) void k_gx(const int* __restrict__ items,
                                            const float* __restrict__ rew,
                                            const float* __restrict__ table,
                                            const float* __restrict__ Wx,
                                            const float* __restrict__ bx,
                                            float* __restrict__ gx) {
  __shared__ float Wl[96][140];
  __shared__ float Al[16][128];
  __shared__ float rl[16];
  int gt = blockIdx.x & 3, pt = blockIdx.x >> 2;
  int g0 = gt * 96, p0 = pt * 16;
  int t = threadIdx.x;
  for (int i = t; i < 96 * 34; i += 256) {           // 136 cols = 34 float4
    int r = i / 34, c = i % 34;
    f32x4 v = *(const f32x4*)(Wx + (size_t)(g0 + r) * KXX + c * 4);
    *(f32x4*)&Wl[r][c * 4] = v;
  }
  for (int i = t; i < 16 * 32; i += 256) {
    int r = i >> 5, c = i & 31;
    int it = items[p0 + r];
    *(f32x4*)&Al[r][c * 4] = *(const f32x4*)(table + (size_t)it * DD + c * 4);
  }
  if (t < 16) rl[t] = rew[p0 + t];
  __syncthreads();

  int tg = t & 31, pq = (t >> 5) & 7;
  float acc[2][3] = {};
  for (int k4 = 0; k4 < 32; ++k4) {
    f32x4 a0 = *(f32x4*)&Al[pq][k4 * 4];
    f32x4 a1 = *(f32x4*)&Al[pq + 8][k4 * 4];
#pragma unroll
    for (int u = 0; u < 3; ++u) {
      f32x4 w = *(f32x4*)&Wl[tg + 32 * u][k4 * 4];
      acc[0][u] += a0.x * w.x + a0.y * w.y + a0.z * w.z + a0.w * w.w;
      acc[1][u] += a1.x * w.x + a1.y * w.y + a1.z * w.z + a1.w * w.w;
    }
  }
#pragma unroll
  for (int u = 0; u < 3; ++u) {
    int gl = tg + 32 * u, g = g0 + gl;
    float wxr = 0.f;
#pragma unroll
    for (int q = 0; q < 8; ++q) wxr += Wl[gl][128 + q];
    float bxv = bx[g];
#pragma unroll
    for (int i2 = 0; i2 < 2; ++i2) {
      int p = p0 + pq + 8 * i2;
      gx[(size_t)p * G3 + g] = acc[i2][u] + rl[pq + 8 * i2] * wxr + bxv;
    }
  }
}

// ---------------- K5: GRU with register-resident Wh ----------------
__global__ __launch_bounds__(256, 1) void k_gru(const float* __restrict__ gx,
                                                const float* __restrict__ Wh,
                                                const float* __restrict__ bh,
                                                const int* __restrict__ items,
                                                float* __restrict__ sums,
                                                float* __restrict__ counts,
                                                float* __restrict__ hT) {
  __shared__ float hl[4][DD];    // h per row
  __shared__ float ghl[4][G3];   // Wh @ h per row
  int t = threadIdx.x;
  int u = t >> 6, w = t & 63;          // wave, lane
  int gbase = t >> 1, half = t & 1;    // g within gate-block, k-half

  f32x4 wreg[3][16];
#pragma unroll
  for (int tt = 0; tt < 3; ++tt) {
    const float* src = Wh + (size_t)(tt * 128 + gbase) * DD + half * 64;
#pragma unroll
    for (int j4 = 0; j4 < 16; ++j4)
      wreg[tt][j4] = *(const f32x4*)(src + j4 * 4);
  }
  float bh6[6];
#pragma unroll
  for (int q = 0; q < 6; ++q) bh6[q] = bh[w + 64 * q];

  int b = blockIdx.x * 4 + u;
  const float* gxb = gx + (size_t)b * SS * G3;
  hl[u][w] = 0.f; hl[u][w + 64] = 0.f;
  float h0 = 0.f, h1 = 0.f;
  __syncthreads();

  for (int s = 0; s < SS; ++s) {
    // phase 1: all lanes compute gh partials for all 4 rows
#pragma unroll
    for (int r = 0; r < 4; ++r) {
      float a0 = 0.f, a1 = 0.f, a2 = 0.f;
#pragma unroll
      for (int j4 = 0; j4 < 16; ++j4) {
        f32x4 hv = *(f32x4*)&hl[r][half * 64 + j4 * 4];
        a0 += wreg[0][j4].x * hv.x + wreg[0][j4].y * hv.y
            + wreg[0][j4].z * hv.z + wreg[0][j4].w * hv.w;
        a1 += wreg[1][j4].x * hv.x + wreg[1][j4].y * hv.y
            + wreg[1][j4].z * hv.z + wreg[1][j4].w * hv.w;
        a2 += wreg[2][j4].x * hv.x + wreg[2][j4].y * hv.y
            + wreg[2][j4].z * hv.z + wreg[2][j4].w * hv.w;
      }
      a0 += __shfl_xor(a0, 1);
      a1 += __shfl_xor(a1, 1);
      a2 += __shfl_xor(a2, 1);
      if (!half) {
        ghl[r][gbase]       = a0;
        ghl[r][128 + gbase] = a1;
        ghl[r][256 + gbase] = a2;
      }
    }
    __syncthreads();
    // phase 2: wave u updates row u's gates/state
    float gr0 = ghl[u][w]       + bh6[0];
    float gr1 = ghl[u][w + 64]  + bh6[1];
    float gz0 = ghl[u][128 + w] + bh6[2];
    float gz1 = ghl[u][192 + w] + bh6[3];
    float gn0 = ghl[u][256 + w] + bh6[4];
    float gn1 = ghl[u][320 + w] + bh6[5];
    float r0 = sigf(gxb[s * G3 + w]       + gr0);
    float r1 = sigf(gxb[s * G3 + 64 + w]  + gr1);
    float z0 = sigf(gxb[s * G3 + 128 + w] + gz0);
    float z1 = sigf(gxb[s * G3 + 192 + w] + gz1);
    float n0 = tanhf(gxb[s * G3 + 256 + w] + r0 * gn0);
    float n1 = tanhf(gxb[s * G3 + 320 + w] + r1 * gn1);
    h0 = (1.f - z0) * n0 + z0 * h0;
    h1 = (1.f - z1) * n1 + z1 * h1;
    hl[u][w] = h0; hl[u][w + 64] = h1;
    int it = items[b * SS + s];
    atomicAdd(sums + (size_t)it * DD + w, h0);
    atomicAdd(sums + (size_t)it * DD + w + 64, h1);
    if (w == 0) atomicAdd(counts + it, 1.f);
    __syncthreads();
  }
  hT[b * DD + w] = h0;
  hT[b * DD + w + 64] = h1;
}

// ---------------- K6: items_input (bf16) ----------------
__global__ __launch_bounds__(256) void k_items(const float* __restrict__ table,
                                               const float* __restrict__ mem,
                                               const float* __restrict__ sums,
                                               const float* __restrict__ counts,
                                               unsigned short* __restrict__ Ibf) {
  size_t tid = (size_t)blockIdx.x * 256 + threadIdx.x;
  size_t i = tid >> 5; int c = (int)(tid & 31);
  if (i >= NII) return;
  float cnt = counts[i];
  size_t base = i * DD + c * 4;
  f32x4 m  = *(const f32x4*)(mem + base);
  f32x4 tb = *(const f32x4*)(table + base);
  float vx, vy, vz, vw;
  if (cnt > 0.f) {
    f32x4 sm = *(const f32x4*)(sums + base);
    vx = 0.5f * (m.x + sm.x / cnt) + tb.x;
    vy = 0.5f * (m.y + sm.y / cnt) + tb.y;
    vz = 0.5f * (m.z + sm.z / cnt) + tb.z;
    vw = 0.5f * (m.w + sm.w / cnt) + tb.w;
  } else {
    vx = m.x + tb.x; vy = m.y + tb.y; vz = m.z + tb.z; vw = m.w + tb.w;
  }
  unsigned long long pack = (unsigned long long)f2bf(vx)
                          | ((unsigned long long)f2bf(vy) << 16)
                          | ((unsigned long long)f2bf(vz) << 32)
                          | ((unsigned long long)f2bf(vw) << 48);
  *(unsigned long long*)(Ibf + base) = pack;
}

// ---------------- K7: rep (last-write-wins) + U' = hT[rep] @ M  -> bf16 ----------------
__global__ __launch_bounds__(256) void k_uprime(const int* __restrict__ ids,
                                                const float* __restrict__ hT,
                                                const float* __restrict__ M,
                                                unsigned short* __restrict__ Ubf) {
  __shared__ int   idsl[BB];
  __shared__ int   repl[16][16];
  __shared__ float hTl[16][DD];
  int t = threadIdx.x;
  for (int i = t; i < BB; i += 256) idsl[i] = ids[i];
  __syncthreads();
  int b0 = blockIdx.x * 16;
  int p = t >> 4, c = t & 15;
  int myid = idsl[b0 + p];
  int best = -1;
  for (int j = c * 64; j < c * 64 + 64; ++j)
    if (idsl[j] == myid) best = j;
  repl[p][c] = best;
  __syncthreads();
  if (c == 0) {
    int rr = -1;
#pragma unroll
    for (int q = 0; q < 16; ++q) rr = max(rr, repl[p][q]);
    repl[p][0] = rr;
  }
  __syncthreads();
  for (int i = t; i < 16 * 32; i += 256) {
    int rr = i >> 5, c4 = i & 31;
    int src = repl[rr][0];
    *(f32x4*)&hTl[rr][c4 * 4] = *(const f32x4*)(hT + (size_t)src * DD + c4 * 4);
  }
  __syncthreads();
  float acc[8] = {0.f, 0.f, 0.f, 0.f, 0.f, 0.f, 0.f, 0.f};
  for (int k1 = 0; k1 < DD; ++k1) {
    float hv = hTl[p][k1];
#pragma unroll
    for (int u = 0; u < 8; ++u)
      acc[u] = fmaf(hv, M[k1 * DD + c + 16 * u], acc[u]);
  }
#pragma unroll
  for (int u = 0; u < 8; ++u)
    Ubf[(size_t)(b0 + p) * DD + c + 16 * u] = f2bf(acc[u]);
}

// ---------------- K8: out = U' @ I^T  (bf16 MFMA, j-strip persistent-B,
//                    LDS-transpose epilogue for 16B/lane coalesced stores) ----
__device__ __forceinline__ bf16x8 bzero8() {
  bf16x8 z;
#pragma unroll
  for (int e = 0; e < 8; ++e) z[e] = (__bf16)0.f;
  return z;
}

__global__ __launch_bounds__(256) void k_gemm(const unsigned short* __restrict__ Ubf,
                                              const unsigned short* __restrict__ Ibf,
                                              float* __restrict__ out) {
  __shared__ float ldsT[64][68];   // pad 68: row-stride bank advance = 4 -> 2-way max
  int j0 = blockIdx.x * 64;
  int t = threadIdx.x;
  int wv = t >> 6, l = t & 63;
  int wr = wv >> 1, wc = wv & 1;           // wave's 32-row / 32-col quadrant
  int jw = j0 + wc * 32;
  int lr = l & 15, lk = l >> 4;            // row-in-16, k-group-of-8

  // Hoist B fragments: 8 x bf16x8 = 32 VGPRs, reused for all b-chunks
  bf16x8 bfrag[4][2];
  int j0l = jw + lr, j1l = jw + 16 + lr;
#pragma unroll
  for (int kk = 0; kk < 4; ++kk) {
    int k0 = kk * 32 + lk * 8;
    bfrag[kk][0] = (j0l < NII) ? *(const bf16x8*)(Ibf + (size_t)j0l * DD + k0) : bzero8();
    bfrag[kk][1] = (j1l < NII) ? *(const bf16x8*)(Ibf + (size_t)j1l * DD + k0) : bzero8();
  }

  // store-phase indices: thread t stores rows (pp*16 + t>>4), col quad (t&15)*4
  int srow = t >> 4;
  int scol = (t & 15) * 4;
  bool svalid = (j0 + scol + 4 <= NII);    // NII % 4 == 0

  for (int bc = 0; bc < 16; ++bc) {
    int bw = bc * 64 + wr * 32;
    f32x4 acc[2][2];
#pragma unroll
    for (int mi = 0; mi < 2; ++mi)
#pragma unroll
      for (int nj = 0; nj < 2; ++nj) { f32x4 z = {0.f,0.f,0.f,0.f}; acc[mi][nj] = z; }

#pragma unroll
    for (int kk = 0; kk < 4; ++kk) {
      int k0 = kk * 32 + lk * 8;
      bf16x8 a0 = *(const bf16x8*)(Ubf + (size_t)(bw + lr) * DD + k0);
      bf16x8 a1 = *(const bf16x8*)(Ubf + (size_t)(bw + 16 + lr) * DD + k0);
      acc[0][0] = __builtin_amdgcn_mfma_f32_16x16x32_bf16(a0, bfrag[kk][0], acc[0][0], 0, 0, 0);
      acc[0][1] = __builtin_amdgcn_mfma_f32_16x16x32_bf16(a0, bfrag[kk][1], acc[0][1], 0, 0, 0);
      acc[1][0] = __builtin_amdgcn_mfma_f32_16x16x32_bf16(a1, bfrag[kk][0], acc[1][0], 0, 0, 0);
      acc[1][1] = __builtin_amdgcn_mfma_f32_16x16x32_bf16(a1, bfrag[kk][1], acc[1][1], 0, 0, 0);
    }
    // C/D layout: col = lane&15 (j), row = (lane>>4)*4 + reg (b)
    __syncthreads();   // previous iteration's ldsT reads complete
#pragma unroll
    for (int mi = 0; mi < 2; ++mi) {
      int lrow = wr * 32 + mi * 16 + lk * 4;
#pragma unroll
      for (int nj = 0; nj < 2; ++nj) {
        int lcol = wc * 32 + nj * 16 + lr;
#pragma unroll
        for (int q = 0; q < 4; ++q)
          ldsT[lrow + q][lcol] = acc[mi][nj][q];
      }
    }
    __syncthreads();
    if (svalid) {
#pragma unroll
      for (int pp = 0; pp < 4; ++pp) {
        int r = pp * 16 + srow;
        f32x4 v = *(f32x4*)&ldsT[r][scol];
        *(f32x4*)(out + (size_t)(bc * 64 + r) * NII + j0 + scol) = v;
      }
    }
  }
}

extern "C" void kernel_launch(void* const* d_in, const int* in_sizes, int n_in,
                              void* d_out, int out_size, void* d_ws, size_t ws_size,
                              hipStream_t stream) {
  const int*   users_ids   = (const int*)  d_in[0];
  const int*   users_items = (const int*)  d_in[1];
  const float* users_rew   = (const float*)d_in[2];
  const float* items_table = (const float*)d_in[4];
  const float* items_mem   = (const float*)d_in[6];
  const float* Wx  = (const float*)d_in[7];
  const float* Wh  = (const float*)d_in[8];
  const float* bx  = (const float*)d_in[9];
  const float* bh  = (const float*)d_in[10];
  const float* W_u = (const float*)d_in[11];
  const float* W_i = (const float*)d_in[12];
  float* out = (float*)d_out;
  (void)in_sizes; (void)n_in; (void)out_size; (void)ws_size;

  char* ws = (char*)d_ws;
  size_t off = 0;
  auto alloc = [&](size_t bytes) {
    void* p = ws + off;
    off = (off + bytes + 255) & ~(size_t)255;
    return p;
  };
  float* sums   = (float*)alloc(sizeof(float) * (size_t)NII * DD);
  float* counts = (float*)alloc(sizeof(float) * NII);
  float* gx     = (float*)alloc(sizeof(float) * (size_t)BB * SS * G3);
  float* M      = (float*)alloc(sizeof(float) * DD * DD);
  float* hT     = (float*)alloc(sizeof(float) * BB * DD);
  unsigned short* Ubf = (unsigned short*)alloc(sizeof(unsigned short) * BB * DD);
  unsigned short* Ibf = (unsigned short*)alloc(sizeof(unsigned short) * (size_t)NII * DD);

  hipLaunchKernelGGL(k_zero_seg, dim3((BB * SS * 32) / 256), dim3(256), 0, stream,
                     users_items, sums, counts);
  hipLaunchKernelGGL(k_M, dim3(64), dim3(256), 0, stream, W_u, W_i, M);
  hipLaunchKernelGGL(k_gx, dim3((BB * SS / 16) * 4), dim3(256), 0, stream,
                     users_items, users_rew, items_table, Wx, bx, gx);
  hipLaunchKernelGGL(k_gru, dim3(BB / 4), dim3(256), 0, stream,
                     gx, Wh, bh, users_items, sums, counts, hT);
  hipLaunchKernelGGL(k_items, dim3((NII * 32 + 255) / 256), dim3(256), 0, stream,
                     items_table, items_mem, sums, counts, Ibf);
  hipLaunchKernelGGL(k_uprime, dim3(BB / 16), dim3(256), 0, stream,
                     users_ids, hT, M, Ubf);
  hipLaunchKernelGGL(k_gemm, dim3((NII + 63) / 64), dim3(256), 0, stream,
                     Ubf, Ibf, out);
}

// Round 5
// 355.205 us; speedup vs baseline: 3.0931x; 1.0127x over previous
//
#include <hip/hip_runtime.h>
#include <hip/hip_bf16.h>
#include <stdint.h>

#define BB  1024
#define SS  20
#define DD  128
#define G3  384      // 3*D
#define NII 100000
#define KXX 136      // D + R

typedef float  f32x4  __attribute__((ext_vector_type(4)));
typedef __bf16 bf16x8 __attribute__((ext_vector_type(8)));

__device__ __forceinline__ unsigned short f2bf(float x) {
  uint32_t u = __float_as_uint(x);
  uint32_t r = (u + 0x7fffu + ((u >> 16) & 1u)) >> 16;   // RNE
  return (unsigned short)r;
}

__device__ __forceinline__ float sigf(float x) { return 1.f / (1.f + expf(-x)); }

// ---------------- K1: zero sums/counts for touched items ----------------
__global__ __launch_bounds__(256) void k_zero_seg(const int* __restrict__ items,
                                                  float* __restrict__ sums,
                                                  float* __restrict__ counts) {
  int tid = blockIdx.x * 256 + threadIdx.x;
  int p = tid >> 5, c = tid & 31;
  if (p >= BB * SS) return;
  int it = items[p];
  f32x4 z = {0.f, 0.f, 0.f, 0.f};
  *(f32x4*)(sums + (size_t)it * DD + c * 4) = z;
  if (c == 0) counts[it] = 0.f;
}

// ---------------- K3: M = W_u @ W_i^T  (128x128) ----------------
__global__ __launch_bounds__(256) void k_M(const float* __restrict__ Wu,
                                           const float* __restrict__ Wi,
                                           float* __restrict__ M) {
  int idx = blockIdx.x * 256 + threadIdx.x;  // 16384 total
  int k1 = idx >> 7, k2 = idx & 127;
  float acc = 0.f;
  for (int e = 0; e < DD; ++e)
    acc = fmaf(Wu[k1 * DD + e], Wi[k2 * DD + e], acc);
  M[idx] = acc;
}

// ---------------- K4: gx[p][g] = x[p] . Wx[g] + bx[g] ----------------
__global__ __launch_bounds__(256) void k_gx(const int* __restrict__ items,
                                            const float* __restrict__ rew,
                                            const float* __restrict__ table,
                                            const float* __restrict__ Wx,
                                            const float* __restrict__ bx,
                                            float* __restrict__ gx) {
  __shared__ float Wl[96][140];
  __shared__ float Al[16][128];
  __shared__ float rl[16];
  int gt = blockIdx.x & 3, pt = blockIdx.x >> 2;
  int g0 = gt * 96, p0 = pt * 16;
  int t = threadIdx.x;
  for (int i = t; i < 96 * 34; i += 256) {           // 136 cols = 34 float4
    int r = i / 34, c = i % 34;
    f32x4 v = *(const f32x4*)(Wx + (size_t)(g0 + r) * KXX + c * 4);
    *(f32x4*)&Wl[r][c * 4] = v;
  }
  for (int i = t; i < 16 * 32; i += 256) {
    int r = i >> 5, c = i & 31;
    int it = items[p0 + r];
    *(f32x4*)&Al[r][c * 4] = *(const f32x4*)(table + (size_t)it * DD + c * 4);
  }
  if (t < 16) rl[t] = rew[p0 + t];
  __syncthreads();

  int tg = t & 31, pq = (t >> 5) & 7;
  float acc[2][3] = {};
  for (int k4 = 0; k4 < 32; ++k4) {
    f32x4 a0 = *(f32x4*)&Al[pq][k4 * 4];
    f32x4 a1 = *(f32x4*)&Al[pq + 8][k4 * 4];
#pragma unroll
    for (int u = 0; u < 3; ++u) {
      f32x4 w = *(f32x4*)&Wl[tg + 32 * u][k4 * 4];
      acc[0][u] += a0.x * w.x + a0.y * w.y + a0.z * w.z + a0.w * w.w;
      acc[1][u] += a1.x * w.x + a1.y * w.y + a1.z * w.z + a1.w * w.w;
    }
  }
#pragma unroll
  for (int u = 0; u < 3; ++u) {
    int gl = tg + 32 * u, g = g0 + gl;
    float wxr = 0.f;
#pragma unroll
    for (int q = 0; q < 8; ++q) wxr += Wl[gl][128 + q];
    float bxv = bx[g];
#pragma unroll
    for (int i2 = 0; i2 < 2; ++i2) {
      int p = p0 + pq + 8 * i2;
      gx[(size_t)p * G3 + g] = acc[i2][u] + rl[pq + 8 * i2] * wxr + bxv;
    }
  }
}

// ---------------- K5: GRU, register Wh + deferred atomics + gx prefetch ----------------
__global__ __launch_bounds__(256, 1) void k_gru(const float* __restrict__ gx,
                                                const float* __restrict__ Wh,
                                                const float* __restrict__ bh,
                                                const int* __restrict__ items,
                                                float* __restrict__ sums,
                                                float* __restrict__ counts,
                                                float* __restrict__ hT) {
  __shared__ float hl[4][DD];          // h per row
  __shared__ float ghl[4][G3];         // Wh @ h per row
  __shared__ float hist[4][SS][DD];    // 40 KB: h history for deferred atomics
  int t = threadIdx.x;
  int u = t >> 6, w = t & 63;          // wave, lane
  int gbase = t >> 1, half = t & 1;    // g within gate-block, k-half

  f32x4 wreg[3][16];
#pragma unroll
  for (int tt = 0; tt < 3; ++tt) {
    const float* src = Wh + (size_t)(tt * 128 + gbase) * DD + half * 64;
#pragma unroll
    for (int j4 = 0; j4 < 16; ++j4)
      wreg[tt][j4] = *(const f32x4*)(src + j4 * 4);
  }
  float bh6[6];
#pragma unroll
  for (int q = 0; q < 6; ++q) bh6[q] = bh[w + 64 * q];

  int b = blockIdx.x * 4 + u;
  const float* gxb = gx + (size_t)b * SS * G3;
  hl[u][w] = 0.f; hl[u][w + 64] = 0.f;
  float h0 = 0.f, h1 = 0.f;
  __syncthreads();

  for (int s = 0; s < SS; ++s) {
    // issue this step's gx loads NOW; phase-1 FMA chain hides their latency
    float g6[6];
#pragma unroll
    for (int q = 0; q < 6; ++q) g6[q] = gxb[s * G3 + q * 64 + w];

    // phase 1: all lanes compute gh partials for all 4 rows
#pragma unroll
    for (int r = 0; r < 4; ++r) {
      float a0 = 0.f, a1 = 0.f, a2 = 0.f;
#pragma unroll
      for (int j4 = 0; j4 < 16; ++j4) {
        f32x4 hv = *(f32x4*)&hl[r][half * 64 + j4 * 4];
        a0 += wreg[0][j4].x * hv.x + wreg[0][j4].y * hv.y
            + wreg[0][j4].z * hv.z + wreg[0][j4].w * hv.w;
        a1 += wreg[1][j4].x * hv.x + wreg[1][j4].y * hv.y
            + wreg[1][j4].z * hv.z + wreg[1][j4].w * hv.w;
        a2 += wreg[2][j4].x * hv.x + wreg[2][j4].y * hv.y
            + wreg[2][j4].z * hv.z + wreg[2][j4].w * hv.w;
      }
      a0 += __shfl_xor(a0, 1);
      a1 += __shfl_xor(a1, 1);
      a2 += __shfl_xor(a2, 1);
      if (!half) {
        ghl[r][gbase]       = a0;
        ghl[r][128 + gbase] = a1;
        ghl[r][256 + gbase] = a2;
      }
    }
    __syncthreads();
    // phase 2: wave u updates row u's gates/state (no global ops -> no drain)
    float r0 = sigf(g6[0] + ghl[u][w]       + bh6[0]);
    float r1 = sigf(g6[1] + ghl[u][w + 64]  + bh6[1]);
    float z0 = sigf(g6[2] + ghl[u][128 + w] + bh6[2]);
    float z1 = sigf(g6[3] + ghl[u][192 + w] + bh6[3]);
    float n0 = tanhf(g6[4] + r0 * (ghl[u][256 + w] + bh6[4]));
    float n1 = tanhf(g6[5] + r1 * (ghl[u][320 + w] + bh6[5]));
    h0 = (1.f - z0) * n0 + z0 * h0;
    h1 = (1.f - z1) * n1 + z1 * h1;
    hl[u][w] = h0; hl[u][w + 64] = h1;
    hist[u][s][w] = h0; hist[u][s][w + 64] = h1;
    __syncthreads();
  }
  hT[b * DD + w] = h0;
  hT[b * DD + w + 64] = h1;
  // deferred segment atomics: all 40 per lane pipeline, single drain at exit
  for (int s = 0; s < SS; ++s) {
    int it = items[b * SS + s];
    atomicAdd(sums + (size_t)it * DD + w,      hist[u][s][w]);
    atomicAdd(sums + (size_t)it * DD + w + 64, hist[u][s][w + 64]);
    if (w == 0) atomicAdd(counts + it, 1.f);
  }
}

// ---------------- K6: items_input (bf16) ----------------
__global__ __launch_bounds__(256) void k_items(const float* __restrict__ table,
                                               const float* __restrict__ mem,
                                               const float* __restrict__ sums,
                                               const float* __restrict__ counts,
                                               unsigned short* __restrict__ Ibf) {
  size_t tid = (size_t)blockIdx.x * 256 + threadIdx.x;
  size_t i = tid >> 5; int c = (int)(tid & 31);
  if (i >= NII) return;
  float cnt = counts[i];
  size_t base = i * DD + c * 4;
  f32x4 m  = *(const f32x4*)(mem + base);
  f32x4 tb = *(const f32x4*)(table + base);
  float vx, vy, vz, vw;
  if (cnt > 0.f) {
    f32x4 sm = *(const f32x4*)(sums + base);
    vx = 0.5f * (m.x + sm.x / cnt) + tb.x;
    vy = 0.5f * (m.y + sm.y / cnt) + tb.y;
    vz = 0.5f * (m.z + sm.z / cnt) + tb.z;
    vw = 0.5f * (m.w + sm.w / cnt) + tb.w;
  } else {
    vx = m.x + tb.x; vy = m.y + tb.y; vz = m.z + tb.z; vw = m.w + tb.w;
  }
  unsigned long long pack = (unsigned long long)f2bf(vx)
                          | ((unsigned long long)f2bf(vy) << 16)
                          | ((unsigned long long)f2bf(vz) << 32)
                          | ((unsigned long long)f2bf(vw) << 48);
  *(unsigned long long*)(Ibf + base) = pack;
}

// ---------------- K7: rep (last-write-wins) + U' = hT[rep] @ M  -> bf16 ----------------
__global__ __launch_bounds__(256) void k_uprime(const int* __restrict__ ids,
                                                const float* __restrict__ hT,
                                                const float* __restrict__ M,
                                                unsigned short* __restrict__ Ubf) {
  __shared__ int   idsl[BB];
  __shared__ int   repl[16][16];
  __shared__ float hTl[16][DD];
  int t = threadIdx.x;
  for (int i = t; i < BB; i += 256) idsl[i] = ids[i];
  __syncthreads();
  int b0 = blockIdx.x * 16;
  int p = t >> 4, c = t & 15;
  int myid = idsl[b0 + p];
  int best = -1;
  for (int j = c * 64; j < c * 64 + 64; ++j)
    if (idsl[j] == myid) best = j;
  repl[p][c] = best;
  __syncthreads();
  if (c == 0) {
    int rr = -1;
#pragma unroll
    for (int q = 0; q < 16; ++q) rr = max(rr, repl[p][q]);
    repl[p][0] = rr;
  }
  __syncthreads();
  for (int i = t; i < 16 * 32; i += 256) {
    int rr = i >> 5, c4 = i & 31;
    int src = repl[rr][0];
    *(f32x4*)&hTl[rr][c4 * 4] = *(const f32x4*)(hT + (size_t)src * DD + c4 * 4);
  }
  __syncthreads();
  float acc[8] = {0.f, 0.f, 0.f, 0.f, 0.f, 0.f, 0.f, 0.f};
  for (int k1 = 0; k1 < DD; ++k1) {
    float hv = hTl[p][k1];
#pragma unroll
    for (int u = 0; u < 8; ++u)
      acc[u] = fmaf(hv, M[k1 * DD + c + 16 * u], acc[u]);
  }
#pragma unroll
  for (int u = 0; u < 8; ++u)
    Ubf[(size_t)(b0 + p) * DD + c + 16 * u] = f2bf(acc[u]);
}

// ---------------- K8: out = U' @ I^T  (swapped-operand MFMA: D[j][b],
//   lane holds 4 consecutive j -> direct f32x4 NT stores, zero barriers) ----
__device__ __forceinline__ bf16x8 bzero8() {
  bf16x8 z;
#pragma unroll
  for (int e = 0; e < 8; ++e) z[e] = (__bf16)0.f;
  return z;
}

__global__ __launch_bounds__(256) void k_gemm(const unsigned short* __restrict__ Ubf,
                                              const unsigned short* __restrict__ Ibf,
                                              float* __restrict__ out) {
  int j0 = blockIdx.x * 64;
  int t = threadIdx.x;
  int wv = t >> 6, l = t & 63;
  int wr = wv >> 1, wc = wv & 1;           // wave's 32-b-row / 32-j-col quadrant
  int jw = j0 + wc * 32;
  int lr = l & 15, lk = l >> 4;            // lane row-in-16, k-group-of-8

  // Persistent A fragments = Ibf rows (the j strip), 32 VGPRs
  bf16x8 afrag[4][2];
  int ja0 = jw + lr, ja1 = jw + 16 + lr;
#pragma unroll
  for (int kk = 0; kk < 4; ++kk) {
    int k0 = kk * 32 + lk * 8;
    afrag[kk][0] = (ja0 < NII) ? *(const bf16x8*)(Ibf + (size_t)ja0 * DD + k0) : bzero8();
    afrag[kk][1] = (ja1 < NII) ? *(const bf16x8*)(Ibf + (size_t)ja1 * DD + k0) : bzero8();
  }
  // store j base per lane (row index of D): j = jw + ji*16 + lk*4 + q
  int jb0 = jw + lk * 4;
  bool v0 = (jb0 < NII), v1 = (jb0 + 16 < NII);   // f32x4 fully valid (NII%4==0)

  for (int bc = 0; bc < 16; ++bc) {
    int bw = bc * 64 + wr * 32;
    f32x4 acc[2][2];                       // [ji][bi]
#pragma unroll
    for (int ji = 0; ji < 2; ++ji)
#pragma unroll
      for (int bi = 0; bi < 2; ++bi) { f32x4 z = {0.f,0.f,0.f,0.f}; acc[ji][bi] = z; }

#pragma unroll
    for (int kk = 0; kk < 4; ++kk) {
      int k0 = kk * 32 + lk * 8;
      bf16x8 b0 = *(const bf16x8*)(Ubf + (size_t)(bw + lr) * DD + k0);
      bf16x8 b1 = *(const bf16x8*)(Ubf + (size_t)(bw + 16 + lr) * DD + k0);
      acc[0][0] = __builtin_amdgcn_mfma_f32_16x16x32_bf16(afrag[kk][0], b0, acc[0][0], 0, 0, 0);
      acc[0][1] = __builtin_amdgcn_mfma_f32_16x16x32_bf16(afrag[kk][0], b1, acc[0][1], 0, 0, 0);
      acc[1][0] = __builtin_amdgcn_mfma_f32_16x16x32_bf16(afrag[kk][1], b0, acc[1][0], 0, 0, 0);
      acc[1][1] = __builtin_amdgcn_mfma_f32_16x16x32_bf16(afrag[kk][1], b1, acc[1][1], 0, 0, 0);
    }
    // D layout (swapped): col=lane&15 -> b = bw + bi*16 + lr
    //                     row=(lane>>4)*4+q -> j = jw + ji*16 + lk*4 + q
#pragma unroll
    for (int ji = 0; ji < 2; ++ji) {
      if (ji ? v1 : v0) {
        int jb = jw + ji * 16 + lk * 4;
#pragma unroll
        for (int bi = 0; bi < 2; ++bi) {
          int bb = bw + bi * 16 + lr;
          __builtin_nontemporal_store(acc[ji][bi],
              (f32x4*)(out + (size_t)bb * NII + jb));
        }
      }
    }
  }
}

extern "C" void kernel_launch(void* const* d_in, const int* in_sizes, int n_in,
                              void* d_out, int out_size, void* d_ws, size_t ws_size,
                              hipStream_t stream) {
  const int*   users_ids   = (const int*)  d_in[0];
  const int*   users_items = (const int*)  d_in[1];
  const float* users_rew   = (const float*)d_in[2];
  const float* items_table = (const float*)d_in[4];
  const float* items_mem   = (const float*)d_in[6];
  const float* Wx  = (const float*)d_in[7];
  const float* Wh  = (const float*)d_in[8];
  const float* bx  = (const float*)d_in[9];
  const float* bh  = (const float*)d_in[10];
  const float* W_u = (const float*)d_in[11];
  const float* W_i = (const float*)d_in[12];
  float* out = (float*)d_out;
  (void)in_sizes; (void)n_in; (void)out_size; (void)ws_size;

  char* ws = (char*)d_ws;
  size_t off = 0;
  auto alloc = [&](size_t bytes) {
    void* p = ws + off;
    off = (off + bytes + 255) & ~(size_t)255;
    return p;
  };
  float* sums   = (float*)alloc(sizeof(float) * (size_t)NII * DD);
  float* counts = (float*)alloc(sizeof(float) * NII);
  float* gx     = (float*)alloc(sizeof(float) * (size_t)BB * SS * G3);
  float* M      = (float*)alloc(sizeof(float) * DD * DD);
  float* hT     = (float*)alloc(sizeof(float) * BB * DD);
  unsigned short* Ubf = (unsigned short*)alloc(sizeof(unsigned short) * BB * DD);
  unsigned short* Ibf = (unsigned short*)alloc(sizeof(unsigned short) * (size_t)NII * DD);

  hipLaunchKernelGGL(k_zero_seg, dim3((BB * SS * 32) / 256), dim3(256), 0, stream,
                     users_items, sums, counts);
  hipLaunchKernelGGL(k_M, dim3(64), dim3(256), 0, stream, W_u, W_i, M);
  hipLaunchKernelGGL(k_gx, dim3((BB * SS / 16) * 4), dim3(256), 0, stream,
                     users_items, users_rew, items_table, Wx, bx, gx);
  hipLaunchKernelGGL(k_gru, dim3(BB / 4), dim3(256), 0, stream,
                     gx, Wh, bh, users_items, sums, counts, hT);
  hipLaunchKernelGGL(k_items, dim3((NII * 32 + 255) / 256), dim3(256), 0, stream,
                     items_table, items_mem, sums, counts, Ibf);
  hipLaunchKernelGGL(k_uprime, dim3(BB / 16), dim3(256), 0, stream,
                     users_ids, hT, M, Ubf);
  hipLaunchKernelGGL(k_gemm, dim3((NII + 63) / 64), dim3(256), 0, stream,
                     Ubf, Ibf, out);
}